// Round 3
// baseline (96.883 us; speedup 1.0000x reference)
//
#include <hip/hip_runtime.h>
#include <math.h>

// CoordinateDecoder via f16 MFMA (v_mfma_f32_32x32x16_f16).
// R15 = R14 + {bias-slice MFMA folding: cond biases become per-image f16
// A-fragments (hi+lo split for fp32-accurate bias) appended to the
// fragment table; acc init = mfma(bias_frag, bones, 0) where bones is a
// constant B-fragment (1.0 at k=0,1). Removes ~50 broadcast ds_read_b128
// per wave (init_acc + scb) that were delivering 16 useful bytes per 1KB
// of LDS return bus -- decoder was LDS-return-bus bound (96KB/wave ~= 18
// kcyc/CU ~= 7.5us = observed). New bus load ~62KB/wave -> ~4.9us floor.}
// Split-barrier pipelined staging kept: issue order cc(4), bias(2),
// g1=L1+L2(3), g2=L3+L4(3); barrier1 = vmcnt(3), barrier2 = vmcnt(0).
// Measured context: ~83us of harness dur_us is two 268MB workspace
// re-poison fills (~82% HBM peak) -- untouchable.
// k-axis permutation trick: pi(16kt+8q+reg)=32(kt>>1)+16(kt&1)+8(reg>>2)+4q+(reg&3)
// makes C/D register layout == next layer's B-fragment layout (no cross-lane
// ops). sqrt(2) folded into next-layer weights.

typedef _Float16 half2v __attribute__((ext_vector_type(2)));
typedef __fp16   fp16x2 __attribute__((ext_vector_type(2)));
typedef _Float16 half4v __attribute__((ext_vector_type(4)));
typedef _Float16 half8  __attribute__((ext_vector_type(8)));
typedef float f32x16 __attribute__((ext_vector_type(16)));

#define SCALE1 0.0790569415042094833f  // 1/sqrt(160)
#define SCALE2 0.0721687836487032206f  // 1/sqrt(192)
#define SQRT2F 1.41421356237309515f

// fragment region: half8 entries (16B each). tile entry = (mt*Kt+kt)*64+lane
#define FE_L1 0      // Mt=2, Kt=2 -> 4*64
#define FE_L2 256    // Mt=2, Kt=4 -> 8*64
#define FE_L3 768    // Mt=2, Kt=4 -> 8*64
#define FE_L4 1280   // Mt=1, Kt=4 -> 4*64 (rows j>=4 zeroed)
#define FE_TOT 1536  // 24576 B
// bias-fragment region: per image 8 tile-entries (512 half8s):
//   entry 0,1 = L1 mt0/1; 2,3 = L2; 4,5 = L3; 6 = L4; 7 = pad (zero).
//   lane j&31 (q=0): half8 = {hi, lo, 0...}; all else zero.
#define BE_BASE 1536           // half8 index of bias region (LDS and global)
#define BIAS_PER_IMG 512       // half8s per image

__global__ __launch_bounds__(256) void prep_kernel(
    const float* __restrict__ c, const float* __restrict__ fu,
    const float* __restrict__ w1, const float* __restrict__ b1,
    const float* __restrict__ w2, const float* __restrict__ b2,
    const float* __restrict__ w3, const float* __restrict__ b3,
    const float* __restrict__ w4, const float* __restrict__ b4,
    float* __restrict__ ws)
{
  int t = blockIdx.x * 256 + threadIdx.x;
  if (t < 12288) {
    // weight A-fragment packing, f16
    _Float16* fr = (_Float16*)ws;
    int e, Ktm;
    const float* w; float scale; int stride; bool perm;
    if (t < 2048)       { e = t;         Ktm = 2; w = w1; scale = SCALE1;          stride = 160; perm = false; }
    else if (t < 6144)  { e = t - 2048;  Ktm = 4; w = w2; scale = SCALE2 * SQRT2F; stride = 192; perm = true;  }
    else if (t < 10240) { e = t - 6144;  Ktm = 4; w = w3; scale = SCALE2 * SQRT2F; stride = 192; perm = true;  }
    else                { e = t - 10240; Ktm = 4; w = w4; scale = SCALE2 * SQRT2F; stride = 192; perm = true;  }
    int til  = e >> 9;           // (mt*Kt+kt)
    int lane = (e >> 3) & 63;
    int r    = e & 7;            // reg within half8
    int q    = lane >> 5;
    int mt = til / Ktm, kt = til - mt * Ktm;
    int j = 32 * mt + (lane & 31);
    int k;
    if (perm) {
      k = 32 * (kt >> 1) + 16 * (kt & 1) + 8 * (r >> 2) + 4 * q + (r & 3);
    } else {
      k = 16 * kt + 8 * q + r;   // layer-1 embedding order (identity)
    }
    float val;
    if (t < 2048) {
      float mw = (fu[0] - (float)((k >> 2) + 1) * (1.0f / 9.0f)) * 9.0f;
      mw = fminf(fmaxf(mw, 0.0f), 1.0f);
      val = w[j * stride + k] * scale * mw;
    } else if (t >= 10240) {
      val = (j < 4) ? w[j * stride + k] * scale : 0.0f;  // mt==0 only
    } else {
      val = w[j * stride + k] * scale;
    }
    fr[t] = (_Float16)val;
  } else if (t < 18560) {
    // per-(batch, output) conditioning dot products -> bias A-fragments.
    // 4 threads per dot + shfl_xor reduce; part0 writes half8{hi,lo,0..}.
    int u = t - 12288;           // < 6272 = 1568 dots * 4
    int d = u >> 2, part = u & 3;
    const float* wr; float bias; float scale;
    int b, j, entry, lidx;
    if (d < 1536) {
      int grp = d >> 9;
      b = (d & 511) >> 6; j = d & 63;
      if (grp == 0)      { wr = w1 + j * 160 + 32; bias = b1[j]; scale = SCALE1; }
      else if (grp == 1) { wr = w2 + j * 192 + 64; bias = b2[j]; scale = SCALE2; }
      else               { wr = w3 + j * 192 + 64; bias = b3[j]; scale = SCALE2; }
      entry = grp * 2 + (j >> 5); lidx = j & 31;
    } else {
      int u2 = d - 1536;         // < 32
      b = u2 >> 2; j = u2 & 3;
      wr = w4 + j * 192 + 64; bias = b4[j]; scale = SCALE2;
      entry = 6; lidx = j;
    }
    const float4* wv = (const float4*)wr + part * 8;
    const float4* cv = (const float4*)(c + b * 128) + part * 8;
    float4 s = make_float4(0.f, 0.f, 0.f, 0.f);
    #pragma unroll
    for (int k = 0; k < 8; ++k) {
      float4 a = wv[k], dd = cv[k];
      s.x = fmaf(a.x, dd.x, s.x);
      s.y = fmaf(a.y, dd.y, s.y);
      s.z = fmaf(a.z, dd.z, s.z);
      s.w = fmaf(a.w, dd.w, s.w);
    }
    float v = (s.x + s.y) + (s.z + s.w);
    v += __shfl_xor(v, 1);
    v += __shfl_xor(v, 2);
    if (part == 0) {
      float vf = fmaf(scale, v, bias);
      _Float16 hi16 = (_Float16)vf;
      _Float16 lo16 = (_Float16)(vf - (float)hi16);
      half8 o = {};
      o[0] = hi16; o[1] = lo16;
      ((half8*)ws)[BE_BASE + b * BIAS_PER_IMG + entry * 64 + lidx] = o;
    }
  } else {
    // zero the uncovered parts of the bias-fragment region:
    // entries 0..6 q=1 lanes (7*32), entry6 q=0 lanes 4..31 (28),
    // entry7 all lanes (64) -> 316 half8s per image * 8 images = 2528
    int u = t - 18560;
    if (u >= 2528) return;
    int img = u / 316, rem = u - img * 316;
    int entry, lidx;
    if (rem < 224)      { entry = rem >> 5; lidx = 32 + (rem & 31); }
    else if (rem < 252) { entry = 6;        lidx = 4 + (rem - 224); }
    else                { entry = 7;        lidx = rem - 252; }
    half8 z8 = {};
    ((half8*)ws)[BE_BASE + img * BIAS_PER_IMG + entry * 64 + lidx] = z8;
  }
}

#define WAIT_VM3() asm volatile("s_waitcnt vmcnt(3)" ::: "memory")
#define WAIT_VM0() asm volatile("s_waitcnt vmcnt(0)" ::: "memory")

__global__ __launch_bounds__(256, 4) void decoder_main(
    const float2* __restrict__ coords, const float* __restrict__ ws,
    float4* __restrict__ out)
{
  __shared__ __align__(16) _Float16 sfr_raw[(FE_TOT + BIAS_PER_IMG) * 8];  // 32768 B
  half8* __restrict__ sfr = (half8*)sfr_raw;

  const int tid  = threadIdx.x;
  const int lane = tid & 63;
  const int wave = tid >> 6;
  const int b    = blockIdx.x >> 7;   // 512 px/block, 65536 px/image
  const int col  = lane & 31;
  const bool hi  = lane >= 32;        // q = lane>>5

  // ---- issue order (pinned): coords(4), bias frags(2), g1=L1+L2(3),
  // g2=L3+L4(3). Per-wave queue after full issue (oldest first):
  // [cc x4, bias x2, g1 x3, g2 x3]. vmcnt(3) => cc+bias+g1 complete.
  const float2* __restrict__ cptr = coords + blockIdx.x * 512 + wave * 64;
  float2 cc[2][2];  // [tile][nt]
  cc[0][0] = cptr[col];       cc[0][1] = cptr[32 + col];
  cc[1][0] = cptr[256 + col]; cc[1][1] = cptr[288 + col];
  __builtin_amdgcn_sched_barrier(0);

  const half8* __restrict__ gfr = (const half8*)ws;
  // bias frags: 512 half8s, 2 wave-issues each (LDS idx == global idx - b*512)
  #pragma unroll
  for (int e = 0; e < 2; ++e) {
    const int eL = BE_BASE + wave * 128 + 64 * e;   // LDS half8 base
    __builtin_amdgcn_global_load_lds(
        (const __attribute__((address_space(1))) void*)(gfr + b * BIAS_PER_IMG + eL + lane),
        (__attribute__((address_space(3))) void*)(sfr_raw + eL * 8),
        16, 0, 0);
  }
  __builtin_amdgcn_sched_barrier(0);
  // g1: entries 0..767 = FE_L1 + FE_L2
  #pragma unroll
  for (int i = 0; i < 3; ++i) {
    const int e0 = wave * 64 + 256 * i;   // wave-uniform entry base
    __builtin_amdgcn_global_load_lds(
        (const __attribute__((address_space(1))) void*)(gfr + e0 + lane),
        (__attribute__((address_space(3))) void*)(sfr_raw + e0 * 8),
        16, 0, 0);
  }
  __builtin_amdgcn_sched_barrier(0);
  // g2: entries 768..1535 = FE_L3 + FE_L4
  #pragma unroll
  for (int i = 3; i < 6; ++i) {
    const int e0 = wave * 64 + 256 * i;
    __builtin_amdgcn_global_load_lds(
        (const __attribute__((address_space(1))) void*)(gfr + e0 + lane),
        (__attribute__((address_space(3))) void*)(sfr_raw + e0 * 8),
        16, 0, 0);
  }
  __builtin_amdgcn_sched_barrier(0);

  // constant B-fragment for the bias K-slice: B[0][n]=B[1][n]=1
  // (q=0 lanes, elements 0,1). Effective bias = hi + lo (fp32-accurate).
  half8 bones = {};
  if (!hi) { bones[0] = (_Float16)1.0f; bones[1] = (_Float16)1.0f; }
  const f32x16 z = {};  // zero C operand for bias-init MFMAs

  f32x16 acc[2][2];  // [mt][nt]
  half8 nbf[2][4];   // [nt][kt]

  // transition: pkrtz raw acc -> packed-f16 lrelu (pk_mul + pk_max)
  auto transition = [&]() {
    #pragma unroll
    for (int mt = 0; mt < 2; ++mt)
      #pragma unroll
      for (int nt = 0; nt < 2; ++nt) {
        #pragma unroll
        for (int h = 0; h < 2; ++h) {
          half2v pp[4];
          #pragma unroll
          for (int p = 0; p < 4; ++p) {
            fp16x2 t = __builtin_amdgcn_cvt_pkrtz(acc[mt][nt][8 * h + 2 * p],
                                                  acc[mt][nt][8 * h + 2 * p + 1]);
            pp[p] = __builtin_bit_cast(half2v, t);
          }
          half4v q0 = __builtin_shufflevector(pp[0], pp[1], 0, 1, 2, 3);
          half4v q1 = __builtin_shufflevector(pp[2], pp[3], 0, 1, 2, 3);
          half8 f = __builtin_shufflevector(q0, q1, 0, 1, 2, 3, 4, 5, 6, 7);
          half8 f2 = f * (_Float16)0.2f;           // v_pk_mul_f16
          nbf[nt][2 * mt + h] = __builtin_elementwise_max(f, f2);  // v_pk_max_f16
        }
      }
  };

  #pragma unroll
  for (int t = 0; t < 2; ++t) {
    // ---- layer-1 B fragments: sinusoidal embedding, double-angle chain --
    half8 bf[2][2];  // [nt][kt]
    float mm[2];     // radius mask per nt (precomputed; frees cc[t] early)
    {
      const float qm = hi ? 0.4f : 0.1f;  // 0.1 * 2^(2q)
      auto chain = [](float a, float* s, float* c) {
        float s0 = __sinf(a), c0 = __cosf(a);
        s[0] = s0; c[0] = c0;
        float s1 = 2.f * s0 * c0, c1 = (c0 - s0) * (c0 + s0);
        s[1] = s1; c[1] = c1;
        float s2 = 2.f * s1 * c1, c2 = (c1 - s1) * (c1 + s1);
        float s3 = 2.f * s2 * c2, c3 = (c2 - s2) * (c2 + s2);
        float s4 = 2.f * s3 * c3, c4 = (c3 - s3) * (c3 + s3);
        s[2] = s4; c[2] = c4;
        float s5 = 2.f * s4 * c4, c5 = (c4 - s4) * (c4 + s4);
        s[3] = s5; c[3] = c5;
      };
      #pragma unroll
      for (int nt = 0; nt < 2; ++nt) {
        const float2 ccv = cc[t][nt];
        const float rad = sqrtf(ccv.x * ccv.x + ccv.y * ccv.y);
        const float tt = fmaxf(rad - 1.0f, 0.0f);
        mm[nt] = 2.0f / (__expf(2.0f * tt) + 1.0f);
        float sx[4], cx[4], sy[4], cy[4];
        chain(ccv.x * qm, sx, cx);
        chain(ccv.y * qm, sy, cy);
        #pragma unroll
        for (int kt = 0; kt < 2; ++kt) {
          const int i0 = 2 * kt, i1 = 2 * kt + 1;
          half2v p0v = __builtin_bit_cast(half2v, __builtin_amdgcn_cvt_pkrtz(sx[i0], sy[i0]));
          half2v p1v = __builtin_bit_cast(half2v, __builtin_amdgcn_cvt_pkrtz(cx[i0], cy[i0]));
          half2v p2v = __builtin_bit_cast(half2v, __builtin_amdgcn_cvt_pkrtz(sx[i1], sy[i1]));
          half2v p3v = __builtin_bit_cast(half2v, __builtin_amdgcn_cvt_pkrtz(cx[i1], cy[i1]));
          half4v q0 = __builtin_shufflevector(p0v, p1v, 0, 1, 2, 3);
          half4v q1 = __builtin_shufflevector(p2v, p3v, 0, 1, 2, 3);
          bf[nt][kt] = __builtin_shufflevector(q0, q1, 0, 1, 2, 3, 4, 5, 6, 7);
        }
      }
    }

    if (t == 0) {
      // barrier #1: cc + bias frags + g1 (L1+L2) complete; g2 in flight
      WAIT_VM3();
      __builtin_amdgcn_s_barrier();
      __builtin_amdgcn_sched_barrier(0);
    }

    // ---- layer 1: bias-init MFMA + K=32 (Kt=2) ----
    {
      half8 ba0 = sfr[BE_BASE + 0 * 64 + lane];
      half8 ba1 = sfr[BE_BASE + 1 * 64 + lane];
      acc[0][0] = __builtin_amdgcn_mfma_f32_32x32x16_f16(ba0, bones, z, 0, 0, 0);
      acc[0][1] = __builtin_amdgcn_mfma_f32_32x32x16_f16(ba0, bones, z, 0, 0, 0);
      acc[1][0] = __builtin_amdgcn_mfma_f32_32x32x16_f16(ba1, bones, z, 0, 0, 0);
      acc[1][1] = __builtin_amdgcn_mfma_f32_32x32x16_f16(ba1, bones, z, 0, 0, 0);
    }
    #pragma unroll
    for (int kt = 0; kt < 2; ++kt) {
      half8 a0 = sfr[FE_L1 + (0 * 2 + kt) * 64 + lane];
      half8 a1 = sfr[FE_L1 + (1 * 2 + kt) * 64 + lane];
      acc[0][0] = __builtin_amdgcn_mfma_f32_32x32x16_f16(a0, bf[0][kt], acc[0][0], 0, 0, 0);
      acc[0][1] = __builtin_amdgcn_mfma_f32_32x32x16_f16(a0, bf[1][kt], acc[0][1], 0, 0, 0);
      acc[1][0] = __builtin_amdgcn_mfma_f32_32x32x16_f16(a1, bf[0][kt], acc[1][0], 0, 0, 0);
      acc[1][1] = __builtin_amdgcn_mfma_f32_32x32x16_f16(a1, bf[1][kt], acc[1][1], 0, 0, 0);
    }
    transition();

    // ---- layer 2: bias-init + K=64 (Kt=4) ----
    {
      half8 ba0 = sfr[BE_BASE + 2 * 64 + lane];
      half8 ba1 = sfr[BE_BASE + 3 * 64 + lane];
      acc[0][0] = __builtin_amdgcn_mfma_f32_32x32x16_f16(ba0, bones, z, 0, 0, 0);
      acc[0][1] = __builtin_amdgcn_mfma_f32_32x32x16_f16(ba0, bones, z, 0, 0, 0);
      acc[1][0] = __builtin_amdgcn_mfma_f32_32x32x16_f16(ba1, bones, z, 0, 0, 0);
      acc[1][1] = __builtin_amdgcn_mfma_f32_32x32x16_f16(ba1, bones, z, 0, 0, 0);
    }
    #pragma unroll
    for (int kt = 0; kt < 4; ++kt) {
      half8 a0 = sfr[FE_L2 + (0 * 4 + kt) * 64 + lane];
      half8 a1 = sfr[FE_L2 + (1 * 4 + kt) * 64 + lane];
      acc[0][0] = __builtin_amdgcn_mfma_f32_32x32x16_f16(a0, nbf[0][kt], acc[0][0], 0, 0, 0);
      acc[0][1] = __builtin_amdgcn_mfma_f32_32x32x16_f16(a0, nbf[1][kt], acc[0][1], 0, 0, 0);
      acc[1][0] = __builtin_amdgcn_mfma_f32_32x32x16_f16(a1, nbf[0][kt], acc[1][0], 0, 0, 0);
      acc[1][1] = __builtin_amdgcn_mfma_f32_32x32x16_f16(a1, nbf[1][kt], acc[1][1], 0, 0, 0);
    }
    transition();

    if (t == 0) {
      // barrier #2: all staging (g2 = L3+L4 frags) complete
      WAIT_VM0();
      __builtin_amdgcn_s_barrier();
      __builtin_amdgcn_sched_barrier(0);
    }

    // ---- layer 3: bias-init + K=64 (Kt=4) ----
    {
      half8 ba0 = sfr[BE_BASE + 4 * 64 + lane];
      half8 ba1 = sfr[BE_BASE + 5 * 64 + lane];
      acc[0][0] = __builtin_amdgcn_mfma_f32_32x32x16_f16(ba0, bones, z, 0, 0, 0);
      acc[0][1] = __builtin_amdgcn_mfma_f32_32x32x16_f16(ba0, bones, z, 0, 0, 0);
      acc[1][0] = __builtin_amdgcn_mfma_f32_32x32x16_f16(ba1, bones, z, 0, 0, 0);
      acc[1][1] = __builtin_amdgcn_mfma_f32_32x32x16_f16(ba1, bones, z, 0, 0, 0);
    }
    #pragma unroll
    for (int kt = 0; kt < 4; ++kt) {
      half8 a0 = sfr[FE_L3 + (0 * 4 + kt) * 64 + lane];
      half8 a1 = sfr[FE_L3 + (1 * 4 + kt) * 64 + lane];
      acc[0][0] = __builtin_amdgcn_mfma_f32_32x32x16_f16(a0, nbf[0][kt], acc[0][0], 0, 0, 0);
      acc[0][1] = __builtin_amdgcn_mfma_f32_32x32x16_f16(a0, nbf[1][kt], acc[0][1], 0, 0, 0);
      acc[1][0] = __builtin_amdgcn_mfma_f32_32x32x16_f16(a1, nbf[0][kt], acc[1][0], 0, 0, 0);
      acc[1][1] = __builtin_amdgcn_mfma_f32_32x32x16_f16(a1, nbf[1][kt], acc[1][1], 0, 0, 0);
    }
    transition();

    // ---- layer 4: bias-init + 64 -> 4 ----
    f32x16 acc4[2];
    {
      half8 ba = sfr[BE_BASE + 6 * 64 + lane];
      acc4[0] = __builtin_amdgcn_mfma_f32_32x32x16_f16(ba, bones, z, 0, 0, 0);
      acc4[1] = __builtin_amdgcn_mfma_f32_32x32x16_f16(ba, bones, z, 0, 0, 0);
    }
    #pragma unroll
    for (int kt = 0; kt < 4; ++kt) {
      half8 a0 = sfr[FE_L4 + kt * 64 + lane];
      acc4[0] = __builtin_amdgcn_mfma_f32_32x32x16_f16(a0, nbf[0][kt], acc4[0], 0, 0, 0);
      acc4[1] = __builtin_amdgcn_mfma_f32_32x32x16_f16(a0, nbf[1][kt], acc4[1], 0, 0, 0);
    }

    // epilogue: lanes 0..31 hold channels j=0..3 in regs 0..3
    if (!hi) {
      const int pbase = blockIdx.x * 512 + t * 256 + wave * 64 + col;
      #pragma unroll
      for (int nt = 0; nt < 2; ++nt) {
        const float m = mm[nt];
        out[pbase + 32 * nt] = make_float4(acc4[nt][0] * m, acc4[nt][1] * m,
                                           acc4[nt][2] * m, acc4[nt][3] * m);
      }
    }
  }
}

extern "C" void kernel_launch(void* const* d_in, const int* in_sizes, int n_in,
                              void* d_out, int out_size, void* d_ws, size_t ws_size,
                              hipStream_t stream) {
  const float* coords = (const float*)d_in[0];
  const float* c      = (const float*)d_in[1];
  const float* fu     = (const float*)d_in[2];
  const float* w1     = (const float*)d_in[3];
  const float* b1     = (const float*)d_in[4];
  const float* w2     = (const float*)d_in[5];
  const float* b2     = (const float*)d_in[6];
  const float* w3     = (const float*)d_in[7];
  const float* b3     = (const float*)d_in[8];
  const float* w4     = (const float*)d_in[9];
  const float* b4     = (const float*)d_in[10];
  float* ws  = (float*)d_ws;
  float* out = (float*)d_out;

  int npix = in_sizes[0] / 2;  // 8*256*256 = 524288

  // 12288 frag + 6272 dot + 2528 zero threads = 21088 -> 83 blocks
  prep_kernel<<<83, 256, 0, stream>>>(c, fu, w1, b1, w2, b2, w3, b3, w4, b4, ws);
  decoder_main<<<npix / 512, 256, 0, stream>>>(
      (const float2*)coords, ws, (float4*)out);
}

// Round 4
// 95.489 us; speedup vs baseline: 1.0146x; 1.0146x over previous
//
#include <hip/hip_runtime.h>
#include <math.h>

// CoordinateDecoder via f16 MFMA (v_mfma_f32_32x32x16_f16).
// R16 = R14 + {scalar-bias init: cond-bias accumulator init values are
// wave-uniform per q-half (address ws+OFF_CBx+b*64+const is fully
// uniform) -> read via scalar loads (s_load, constant cache) and select
// per-lane with v_cndmask (hi ? p[4+i] : p[i]). Deletes ~50 broadcast
// ds_read_b128/wave that each cost a full 1KB LDS-return-bus slot while
// delivering 16 useful bytes. LDS pipe: 98 -> 48 ops/wave (~7.8 -> ~3.9
// us/CU); added ~200 v_cndmask/wave lands on the underused VALU (~3.0
// us/SIMD). scb staging deleted.}
// R15 post-mortem: bias-as-MFMA folding regressed (+4us) -- identical
// mfma(ba,bones,z) per layer CSE'd into MFMA+16-reg copies and added
// serial C-in latency every wave stalls on; staging +8KB. Reverted.
// Split-barrier pipelined staging kept: per-wave vm queue = [cc x4,
// g1=L1+L2 x3, g2=L3+L4 x3]; barrier1 = vmcnt(3), barrier2 = vmcnt(0).
// sched_barrier(0) after barrier1 keeps bias loads below it (protects
// the counted vmcnt).
// Measured context: ~83us of harness dur_us is two 268MB workspace
// re-poison fills (~82% HBM peak) -- untouchable.
// k-axis permutation trick: pi(16kt+8q+reg)=32(kt>>1)+16(kt&1)+8(reg>>2)+4q+(reg&3)
// makes C/D register layout == next layer's B-fragment layout (no cross-lane
// ops). sqrt(2) folded into next-layer weights; cond halves precomputed as
// fp32 accumulator-init biases by prep_kernel.

typedef _Float16 half2v __attribute__((ext_vector_type(2)));
typedef __fp16   fp16x2 __attribute__((ext_vector_type(2)));
typedef _Float16 half4v __attribute__((ext_vector_type(4)));
typedef _Float16 half8  __attribute__((ext_vector_type(8)));
typedef float f32x16 __attribute__((ext_vector_type(16)));

#define SCALE1 0.0790569415042094833f  // 1/sqrt(160)
#define SCALE2 0.0721687836487032206f  // 1/sqrt(192)
#define SQRT2F 1.41421356237309515f

// fragment region: half8 entries (16B each). tile entry = (mt*Kt+kt)*64+lane
#define FE_L1 0      // Mt=2, Kt=2 -> 4*64
#define FE_L2 256    // Mt=2, Kt=4 -> 8*64
#define FE_L3 768    // Mt=2, Kt=4 -> 8*64
#define FE_L4 1280   // Mt=1, Kt=4 -> 4*64 (rows j>=4 zeroed)
#define FE_TOT 1536  // 24576 B
#define OFF_CB1 6144   // [8][64] fp32 cond bias (incl b1)
#define OFF_CB2 6656
#define OFF_CB3 7168
#define OFF_CB4 7680   // [8][4]

__global__ __launch_bounds__(256) void prep_kernel(
    const float* __restrict__ c, const float* __restrict__ fu,
    const float* __restrict__ w1, const float* __restrict__ b1,
    const float* __restrict__ w2, const float* __restrict__ b2,
    const float* __restrict__ w3, const float* __restrict__ b3,
    const float* __restrict__ w4, const float* __restrict__ b4,
    float* __restrict__ ws)
{
  int t = blockIdx.x * 256 + threadIdx.x;
  if (t < 12288) {
    // weight A-fragment packing, f16
    _Float16* fr = (_Float16*)ws;
    int e, Ktm;
    const float* w; float scale; int stride; bool perm;
    if (t < 2048)       { e = t;         Ktm = 2; w = w1; scale = SCALE1;          stride = 160; perm = false; }
    else if (t < 6144)  { e = t - 2048;  Ktm = 4; w = w2; scale = SCALE2 * SQRT2F; stride = 192; perm = true;  }
    else if (t < 10240) { e = t - 6144;  Ktm = 4; w = w3; scale = SCALE2 * SQRT2F; stride = 192; perm = true;  }
    else                { e = t - 10240; Ktm = 4; w = w4; scale = SCALE2 * SQRT2F; stride = 192; perm = true;  }
    int til  = e >> 9;           // (mt*Kt+kt)
    int lane = (e >> 3) & 63;
    int r    = e & 7;            // reg within half8
    int q    = lane >> 5;
    int mt = til / Ktm, kt = til - mt * Ktm;
    int j = 32 * mt + (lane & 31);
    int k;
    if (perm) {
      k = 32 * (kt >> 1) + 16 * (kt & 1) + 8 * (r >> 2) + 4 * q + (r & 3);
    } else {
      k = 16 * kt + 8 * q + r;   // layer-1 embedding order (identity)
    }
    float val;
    if (t < 2048) {
      float mw = (fu[0] - (float)((k >> 2) + 1) * (1.0f / 9.0f)) * 9.0f;
      mw = fminf(fmaxf(mw, 0.0f), 1.0f);
      val = w[j * stride + k] * scale * mw;
    } else if (t >= 10240) {
      val = (j < 4) ? w[j * stride + k] * scale : 0.0f;  // mt==0 only
    } else {
      val = w[j * stride + k] * scale;
    }
    fr[t] = (_Float16)val;
  } else {
    // per-(batch, output) conditioning dot products (fp32),
    // 4 threads per dot + shfl_xor reduce
    int u = t - 12288;
    if (u >= 6272) return;       // 1568 dots * 4
    int d = u >> 2, part = u & 3;
    const float* wr; float bias; float scale; int outoff;
    int b, j;
    if (d < 1536) {
      int grp = d >> 9;
      b = (d & 511) >> 6; j = d & 63;
      if (grp == 0)      { wr = w1 + j * 160 + 32; bias = b1[j]; scale = SCALE1; outoff = OFF_CB1 + b * 64 + j; }
      else if (grp == 1) { wr = w2 + j * 192 + 64; bias = b2[j]; scale = SCALE2; outoff = OFF_CB2 + b * 64 + j; }
      else               { wr = w3 + j * 192 + 64; bias = b3[j]; scale = SCALE2; outoff = OFF_CB3 + b * 64 + j; }
    } else {
      int u2 = d - 1536;         // < 32
      b = u2 >> 2; j = u2 & 3;
      wr = w4 + j * 192 + 64; bias = b4[j]; scale = SCALE2; outoff = OFF_CB4 + b * 4 + j;
    }
    const float4* wv = (const float4*)wr + part * 8;
    const float4* cv = (const float4*)(c + b * 128) + part * 8;
    float4 s = make_float4(0.f, 0.f, 0.f, 0.f);
    #pragma unroll
    for (int k = 0; k < 8; ++k) {
      float4 a = wv[k], dd = cv[k];
      s.x = fmaf(a.x, dd.x, s.x);
      s.y = fmaf(a.y, dd.y, s.y);
      s.z = fmaf(a.z, dd.z, s.z);
      s.w = fmaf(a.w, dd.w, s.w);
    }
    float v = (s.x + s.y) + (s.z + s.w);
    v += __shfl_xor(v, 1);
    v += __shfl_xor(v, 2);
    if (part == 0) ws[outoff] = fmaf(scale, v, bias);
  }
}

#define WAIT_VM3() asm volatile("s_waitcnt vmcnt(3)" ::: "memory")
#define WAIT_VM0() asm volatile("s_waitcnt vmcnt(0)" ::: "memory")

__global__ __launch_bounds__(256, 4) void decoder_main(
    const float2* __restrict__ coords, const float* __restrict__ ws,
    float4* __restrict__ out)
{
  __shared__ __align__(16) _Float16 sfr_raw[FE_TOT * 8];  // 24576 B
  half8* __restrict__ sfr = (half8*)sfr_raw;

  const int tid  = threadIdx.x;
  const int lane = tid & 63;
  const int wave = tid >> 6;
  const int b    = blockIdx.x >> 7;   // 512 px/block, 65536 px/image
  const int col  = lane & 31;
  const bool hi  = lane >= 32;        // q = lane>>5

  // ---- issue order (pinned): coords(4), g1=L1+L2(3), g2=L3+L4(3).
  // Per-wave vm queue after full issue (oldest first):
  // [cc x4, g1 x3, g2 x3]. vmcnt(3) => cc+g1 complete, g2 in flight.
  const float2* __restrict__ cptr = coords + blockIdx.x * 512 + wave * 64;
  float2 cc[2][2];  // [tile][nt]
  cc[0][0] = cptr[col];       cc[0][1] = cptr[32 + col];
  cc[1][0] = cptr[256 + col]; cc[1][1] = cptr[288 + col];
  __builtin_amdgcn_sched_barrier(0);

  const half8* __restrict__ gfr = (const half8*)ws;
  // g1: entries 0..767 = FE_L1 + FE_L2
  #pragma unroll
  for (int i = 0; i < 3; ++i) {
    const int e0 = wave * 64 + 256 * i;   // wave-uniform entry base
    __builtin_amdgcn_global_load_lds(
        (const __attribute__((address_space(1))) void*)(gfr + e0 + lane),
        (__attribute__((address_space(3))) void*)(sfr_raw + e0 * 8),
        16, 0, 0);
  }
  __builtin_amdgcn_sched_barrier(0);
  // g2: entries 768..1535 = FE_L3 + FE_L4
  #pragma unroll
  for (int i = 3; i < 6; ++i) {
    const int e0 = wave * 64 + 256 * i;
    __builtin_amdgcn_global_load_lds(
        (const __attribute__((address_space(1))) void*)(gfr + e0 + lane),
        (__attribute__((address_space(3))) void*)(sfr_raw + e0 * 8),
        16, 0, 0);
  }
  __builtin_amdgcn_sched_barrier(0);

  // uniform (scalar) bias base pointers -- all addresses below are
  // wave-uniform, so loads scalarize to s_load through the k-cache.
  const float* __restrict__ cbs1 = ws + OFF_CB1 + b * 64;
  const float* __restrict__ cbs2 = ws + OFF_CB2 + b * 64;
  const float* __restrict__ cbs3 = ws + OFF_CB3 + b * 64;
  const float* __restrict__ cbs4 = ws + OFF_CB4 + b * 4;

  f32x16 acc[2][2];  // [mt][nt]
  half8 nbf[2][4];   // [nt][kt]

  // transition: pkrtz raw acc -> packed-f16 lrelu (pk_mul + pk_max)
  auto transition = [&]() {
    #pragma unroll
    for (int mt = 0; mt < 2; ++mt)
      #pragma unroll
      for (int nt = 0; nt < 2; ++nt) {
        #pragma unroll
        for (int h = 0; h < 2; ++h) {
          half2v pp[4];
          #pragma unroll
          for (int p = 0; p < 4; ++p) {
            fp16x2 t = __builtin_amdgcn_cvt_pkrtz(acc[mt][nt][8 * h + 2 * p],
                                                  acc[mt][nt][8 * h + 2 * p + 1]);
            pp[p] = __builtin_bit_cast(half2v, t);
          }
          half4v q0 = __builtin_shufflevector(pp[0], pp[1], 0, 1, 2, 3);
          half4v q1 = __builtin_shufflevector(pp[2], pp[3], 0, 1, 2, 3);
          half8 f = __builtin_shufflevector(q0, q1, 0, 1, 2, 3, 4, 5, 6, 7);
          half8 f2 = f * (_Float16)0.2f;           // v_pk_mul_f16
          nbf[nt][2 * mt + h] = __builtin_elementwise_max(f, f2);  // v_pk_max_f16
        }
      }
  };

  // acc init from scalar bias loads: per (mt,g) read both q-halves as
  // uniform scalars, per-lane select with one v_cndmask per element.
  auto init_acc = [&](const float* __restrict__ cb) {
    #pragma unroll
    for (int mt = 0; mt < 2; ++mt)
      #pragma unroll
      for (int g = 0; g < 4; ++g) {
        const float* p = cb + 32 * mt + 8 * g;
        #pragma unroll
        for (int i = 0; i < 4; ++i) {
          const float f = hi ? p[4 + i] : p[i];   // s_load + v_cndmask
          acc[mt][0][4 * g + i] = f;
          acc[mt][1][4 * g + i] = f;
        }
      }
  };

  #pragma unroll
  for (int t = 0; t < 2; ++t) {
    // ---- layer-1 B fragments: sinusoidal embedding, double-angle chain --
    half8 bf[2][2];  // [nt][kt]
    float mm[2];     // radius mask per nt
    {
      const float qm = hi ? 0.4f : 0.1f;  // 0.1 * 2^(2q)
      auto chain = [](float a, float* s, float* c) {
        float s0 = __sinf(a), c0 = __cosf(a);
        s[0] = s0; c[0] = c0;
        float s1 = 2.f * s0 * c0, c1 = (c0 - s0) * (c0 + s0);
        s[1] = s1; c[1] = c1;
        float s2 = 2.f * s1 * c1, c2 = (c1 - s1) * (c1 + s1);
        float s3 = 2.f * s2 * c2, c3 = (c2 - s2) * (c2 + s2);
        float s4 = 2.f * s3 * c3, c4 = (c3 - s3) * (c3 + s3);
        s[2] = s4; c[2] = c4;
        float s5 = 2.f * s4 * c4, c5 = (c4 - s4) * (c4 + s4);
        s[3] = s5; c[3] = c5;
      };
      #pragma unroll
      for (int nt = 0; nt < 2; ++nt) {
        const float2 ccv = cc[t][nt];
        const float rad = sqrtf(ccv.x * ccv.x + ccv.y * ccv.y);
        const float tt = fmaxf(rad - 1.0f, 0.0f);
        mm[nt] = 2.0f / (__expf(2.0f * tt) + 1.0f);
        float sx[4], cx[4], sy[4], cy[4];
        chain(ccv.x * qm, sx, cx);
        chain(ccv.y * qm, sy, cy);
        #pragma unroll
        for (int kt = 0; kt < 2; ++kt) {
          const int i0 = 2 * kt, i1 = 2 * kt + 1;
          half2v p0v = __builtin_bit_cast(half2v, __builtin_amdgcn_cvt_pkrtz(sx[i0], sy[i0]));
          half2v p1v = __builtin_bit_cast(half2v, __builtin_amdgcn_cvt_pkrtz(cx[i0], cy[i0]));
          half2v p2v = __builtin_bit_cast(half2v, __builtin_amdgcn_cvt_pkrtz(sx[i1], sy[i1]));
          half2v p3v = __builtin_bit_cast(half2v, __builtin_amdgcn_cvt_pkrtz(cx[i1], cy[i1]));
          half4v q0 = __builtin_shufflevector(p0v, p1v, 0, 1, 2, 3);
          half4v q1 = __builtin_shufflevector(p2v, p3v, 0, 1, 2, 3);
          bf[nt][kt] = __builtin_shufflevector(q0, q1, 0, 1, 2, 3, 4, 5, 6, 7);
        }
      }
    }

    if (t == 0) {
      // barrier #1: cc + g1 (L1+L2 frags) complete; g2 still in flight.
      // sched_barrier keeps the (possibly vector) bias loads BELOW this
      // point so the counted vmcnt stays exact.
      WAIT_VM3();
      __builtin_amdgcn_s_barrier();
      __builtin_amdgcn_sched_barrier(0);
    }

    // ---- layer 1: K=32 (Kt=2) ----
    init_acc(cbs1);
    #pragma unroll
    for (int kt = 0; kt < 2; ++kt) {
      half8 a0 = sfr[FE_L1 + (0 * 2 + kt) * 64 + lane];
      half8 a1 = sfr[FE_L1 + (1 * 2 + kt) * 64 + lane];
      acc[0][0] = __builtin_amdgcn_mfma_f32_32x32x16_f16(a0, bf[0][kt], acc[0][0], 0, 0, 0);
      acc[0][1] = __builtin_amdgcn_mfma_f32_32x32x16_f16(a0, bf[1][kt], acc[0][1], 0, 0, 0);
      acc[1][0] = __builtin_amdgcn_mfma_f32_32x32x16_f16(a1, bf[0][kt], acc[1][0], 0, 0, 0);
      acc[1][1] = __builtin_amdgcn_mfma_f32_32x32x16_f16(a1, bf[1][kt], acc[1][1], 0, 0, 0);
    }
    transition();

    // ---- layer 2: K=64 (Kt=4) ----
    init_acc(cbs2);
    #pragma unroll
    for (int kt = 0; kt < 4; ++kt) {
      half8 a0 = sfr[FE_L2 + (0 * 4 + kt) * 64 + lane];
      half8 a1 = sfr[FE_L2 + (1 * 4 + kt) * 64 + lane];
      acc[0][0] = __builtin_amdgcn_mfma_f32_32x32x16_f16(a0, nbf[0][kt], acc[0][0], 0, 0, 0);
      acc[0][1] = __builtin_amdgcn_mfma_f32_32x32x16_f16(a0, nbf[1][kt], acc[0][1], 0, 0, 0);
      acc[1][0] = __builtin_amdgcn_mfma_f32_32x32x16_f16(a1, nbf[0][kt], acc[1][0], 0, 0, 0);
      acc[1][1] = __builtin_amdgcn_mfma_f32_32x32x16_f16(a1, nbf[1][kt], acc[1][1], 0, 0, 0);
    }
    transition();

    if (t == 0) {
      // barrier #2: all staging (g2 = L3+L4 frags) complete
      WAIT_VM0();
      __builtin_amdgcn_s_barrier();
      __builtin_amdgcn_sched_barrier(0);
    }

    // ---- layer 3: K=64 (Kt=4) ----
    init_acc(cbs3);
    #pragma unroll
    for (int kt = 0; kt < 4; ++kt) {
      half8 a0 = sfr[FE_L3 + (0 * 4 + kt) * 64 + lane];
      half8 a1 = sfr[FE_L3 + (1 * 4 + kt) * 64 + lane];
      acc[0][0] = __builtin_amdgcn_mfma_f32_32x32x16_f16(a0, nbf[0][kt], acc[0][0], 0, 0, 0);
      acc[0][1] = __builtin_amdgcn_mfma_f32_32x32x16_f16(a0, nbf[1][kt], acc[0][1], 0, 0, 0);
      acc[1][0] = __builtin_amdgcn_mfma_f32_32x32x16_f16(a1, nbf[0][kt], acc[1][0], 0, 0, 0);
      acc[1][1] = __builtin_amdgcn_mfma_f32_32x32x16_f16(a1, nbf[1][kt], acc[1][1], 0, 0, 0);
    }
    transition();

    // ---- layer 4: 64 -> 4 ----
    f32x16 acc4[2];
    {
      const float c0 = cbs4[0], c1 = cbs4[1], c2 = cbs4[2], c3 = cbs4[3];
      #pragma unroll
      for (int r = 0; r < 16; ++r) { acc4[0][r] = 0.f; acc4[1][r] = 0.f; }
      if (!hi) {
        acc4[0][0] = c0; acc4[0][1] = c1; acc4[0][2] = c2; acc4[0][3] = c3;
        acc4[1][0] = c0; acc4[1][1] = c1; acc4[1][2] = c2; acc4[1][3] = c3;
      }
    }
    #pragma unroll
    for (int kt = 0; kt < 4; ++kt) {
      half8 a0 = sfr[FE_L4 + kt * 64 + lane];
      acc4[0] = __builtin_amdgcn_mfma_f32_32x32x16_f16(a0, nbf[0][kt], acc4[0], 0, 0, 0);
      acc4[1] = __builtin_amdgcn_mfma_f32_32x32x16_f16(a0, nbf[1][kt], acc4[1], 0, 0, 0);
    }

    // epilogue: lanes 0..31 hold channels j=0..3 in regs 0..3
    if (!hi) {
      const int pbase = blockIdx.x * 512 + t * 256 + wave * 64 + col;
      #pragma unroll
      for (int nt = 0; nt < 2; ++nt) {
        const float m = mm[nt];
        out[pbase + 32 * nt] = make_float4(acc4[nt][0] * m, acc4[nt][1] * m,
                                           acc4[nt][2] * m, acc4[nt][3] * m);
      }
    }
  }
}

extern "C" void kernel_launch(void* const* d_in, const int* in_sizes, int n_in,
                              void* d_out, int out_size, void* d_ws, size_t ws_size,
                              hipStream_t stream) {
  const float* coords = (const float*)d_in[0];
  const float* c      = (const float*)d_in[1];
  const float* fu     = (const float*)d_in[2];
  const float* w1     = (const float*)d_in[3];
  const float* b1     = (const float*)d_in[4];
  const float* w2     = (const float*)d_in[5];
  const float* b2     = (const float*)d_in[6];
  const float* w3     = (const float*)d_in[7];
  const float* b3     = (const float*)d_in[8];
  const float* w4     = (const float*)d_in[9];
  const float* b4     = (const float*)d_in[10];
  float* ws  = (float*)d_ws;
  float* out = (float*)d_out;

  int npix = in_sizes[0] / 2;  // 8*256*256 = 524288

  // 12288 fragment threads + 6272 dot threads = 18560 -> 73 blocks
  prep_kernel<<<73, 256, 0, stream>>>(c, fu, w1, b1, w2, b2, w3, b3, w4, b4, ws);
  decoder_main<<<npix / 512, 256, 0, stream>>>(
      (const float2*)coords, ws, (float4*)out);
}

// Round 5
// 93.059 us; speedup vs baseline: 1.0411x; 1.0261x over previous
//
#include <hip/hip_runtime.h>
#include <math.h>

// CoordinateDecoder via f16 MFMA (v_mfma_f32_32x32x16_f16).
// R17 = revert to R14 (measured best, 92.7us). R15 (bias-as-MFMA, +4.2us)
// and R16 (scalar-select bias, +2.8us) both regressed -> refuted theory
// that broadcast ds_read_b128 bias-init loads were LDS-return-bus bound.
// Lesson: same-address broadcast LDS reads are near-free (no bus slot per
// lane); do NOT "optimize" them away onto VMEM/MFMA pipes.
// Structure (R14): grid 1024 = 4 blocks/CU single round; 2 pixel-tiles
// per block per staging; async global_load_lds width-16 staging; split
// barriers with counted vmcnt: per-wave vm queue = [cc x4, (cb x4 on
// wave3), g1=L1+L2 x3, g2=L3+L4 x3]; barrier1 = vmcnt(3) (cc+cb+g1
// done, g2 in flight under layers 1-2), barrier2 = vmcnt(0).
// Budget: fills 2x~41us untouchable (~82% HBM peak); decoder ~7us vs
// ~5.2us MFMA-pipe floor (96 mfma/wave x 16 waves/CU x 8.07cy); LDS
// ~3.8us; VALU ~2.7us. Remaining headroom < +-2us fill-noise band.
// k-axis permutation trick: pi(16kt+8q+reg)=32(kt>>1)+16(kt&1)+8(reg>>2)+4q+(reg&3)
// makes C/D register layout == next layer's B-fragment layout (no cross-lane
// ops). sqrt(2) folded into next-layer weights; cond halves precomputed as
// fp32 accumulator-init biases by prep_kernel.

typedef _Float16 half2v __attribute__((ext_vector_type(2)));
typedef __fp16   fp16x2 __attribute__((ext_vector_type(2)));
typedef _Float16 half4v __attribute__((ext_vector_type(4)));
typedef _Float16 half8  __attribute__((ext_vector_type(8)));
typedef float f32x16 __attribute__((ext_vector_type(16)));

#define SCALE1 0.0790569415042094833f  // 1/sqrt(160)
#define SCALE2 0.0721687836487032206f  // 1/sqrt(192)
#define SQRT2F 1.41421356237309515f

// fragment region: half8 entries (16B each). tile entry = (mt*Kt+kt)*64+lane
#define FE_L1 0      // Mt=2, Kt=2 -> 4*64
#define FE_L2 256    // Mt=2, Kt=4 -> 8*64
#define FE_L3 768    // Mt=2, Kt=4 -> 8*64
#define FE_L4 1280   // Mt=1, Kt=4 -> 4*64 (rows j>=4 zeroed)
#define FE_TOT 1536  // 24576 B
#define OFF_CB1 6144   // [8][64] fp32 cond bias (incl b1)
#define OFF_CB2 6656
#define OFF_CB3 7168
#define OFF_CB4 7680   // [8][4]

__global__ __launch_bounds__(256) void prep_kernel(
    const float* __restrict__ c, const float* __restrict__ fu,
    const float* __restrict__ w1, const float* __restrict__ b1,
    const float* __restrict__ w2, const float* __restrict__ b2,
    const float* __restrict__ w3, const float* __restrict__ b3,
    const float* __restrict__ w4, const float* __restrict__ b4,
    float* __restrict__ ws)
{
  int t = blockIdx.x * 256 + threadIdx.x;
  if (t < 12288) {
    // weight A-fragment packing, f16
    _Float16* fr = (_Float16*)ws;
    int e, Ktm;
    const float* w; float scale; int stride; bool perm;
    if (t < 2048)       { e = t;         Ktm = 2; w = w1; scale = SCALE1;          stride = 160; perm = false; }
    else if (t < 6144)  { e = t - 2048;  Ktm = 4; w = w2; scale = SCALE2 * SQRT2F; stride = 192; perm = true;  }
    else if (t < 10240) { e = t - 6144;  Ktm = 4; w = w3; scale = SCALE2 * SQRT2F; stride = 192; perm = true;  }
    else                { e = t - 10240; Ktm = 4; w = w4; scale = SCALE2 * SQRT2F; stride = 192; perm = true;  }
    int til  = e >> 9;           // (mt*Kt+kt)
    int lane = (e >> 3) & 63;
    int r    = e & 7;            // reg within half8
    int q    = lane >> 5;
    int mt = til / Ktm, kt = til - mt * Ktm;
    int j = 32 * mt + (lane & 31);
    int k;
    if (perm) {
      k = 32 * (kt >> 1) + 16 * (kt & 1) + 8 * (r >> 2) + 4 * q + (r & 3);
    } else {
      k = 16 * kt + 8 * q + r;   // layer-1 embedding order (identity)
    }
    float val;
    if (t < 2048) {
      float mw = (fu[0] - (float)((k >> 2) + 1) * (1.0f / 9.0f)) * 9.0f;
      mw = fminf(fmaxf(mw, 0.0f), 1.0f);
      val = w[j * stride + k] * scale * mw;
    } else if (t >= 10240) {
      val = (j < 4) ? w[j * stride + k] * scale : 0.0f;  // mt==0 only
    } else {
      val = w[j * stride + k] * scale;
    }
    fr[t] = (_Float16)val;
  } else {
    // per-(batch, output) conditioning dot products (fp32),
    // 4 threads per dot + shfl_xor reduce
    int u = t - 12288;
    if (u >= 6272) return;       // 1568 dots * 4
    int d = u >> 2, part = u & 3;
    const float* wr; float bias; float scale; int outoff;
    int b, j;
    if (d < 1536) {
      int grp = d >> 9;
      b = (d & 511) >> 6; j = d & 63;
      if (grp == 0)      { wr = w1 + j * 160 + 32; bias = b1[j]; scale = SCALE1; outoff = OFF_CB1 + b * 64 + j; }
      else if (grp == 1) { wr = w2 + j * 192 + 64; bias = b2[j]; scale = SCALE2; outoff = OFF_CB2 + b * 64 + j; }
      else               { wr = w3 + j * 192 + 64; bias = b3[j]; scale = SCALE2; outoff = OFF_CB3 + b * 64 + j; }
    } else {
      int u2 = d - 1536;         // < 32
      b = u2 >> 2; j = u2 & 3;
      wr = w4 + j * 192 + 64; bias = b4[j]; scale = SCALE2; outoff = OFF_CB4 + b * 4 + j;
    }
    const float4* wv = (const float4*)wr + part * 8;
    const float4* cv = (const float4*)(c + b * 128) + part * 8;
    float4 s = make_float4(0.f, 0.f, 0.f, 0.f);
    #pragma unroll
    for (int k = 0; k < 8; ++k) {
      float4 a = wv[k], dd = cv[k];
      s.x = fmaf(a.x, dd.x, s.x);
      s.y = fmaf(a.y, dd.y, s.y);
      s.z = fmaf(a.z, dd.z, s.z);
      s.w = fmaf(a.w, dd.w, s.w);
    }
    float v = (s.x + s.y) + (s.z + s.w);
    v += __shfl_xor(v, 1);
    v += __shfl_xor(v, 2);
    if (part == 0) ws[outoff] = fmaf(scale, v, bias);
  }
}

#define WAIT_VM3() asm volatile("s_waitcnt vmcnt(3)" ::: "memory")
#define WAIT_VM0() asm volatile("s_waitcnt vmcnt(0)" ::: "memory")

__global__ __launch_bounds__(256, 4) void decoder_main(
    const float2* __restrict__ coords, const float* __restrict__ ws,
    float4* __restrict__ out)
{
  __shared__ __align__(16) _Float16 sfr_raw[FE_TOT * 8];  // 24576 B
  __shared__ __align__(16) float scb[256];                // staged cond biases
  half8* __restrict__ sfr = (half8*)sfr_raw;

  const int tid  = threadIdx.x;
  const int lane = tid & 63;
  const int wave = tid >> 6;
  const int b    = blockIdx.x >> 7;   // 512 px/block, 65536 px/image
  const int col  = lane & 31;
  const bool hi  = lane >= 32;        // q = lane>>5
  const int q4   = hi ? 4 : 0;

  // ---- issue order (pinned): coords(4), cb (wave3 only, 4), g1=L1+L2(3),
  // g2=L3+L4(3). Per-wave vm queue after full issue (oldest first):
  // waves 0-2 = [cc x4, g1 x3, g2 x3]; wave 3 = [cc x4, cb x4, g1 x3,
  // g2 x3]. vmcnt(3) => cc+cb+g1 complete, g2 in flight.
  const float2* __restrict__ cptr = coords + blockIdx.x * 512 + wave * 64;
  float2 cc[2][2];  // [tile][nt]
  cc[0][0] = cptr[col];       cc[0][1] = cptr[32 + col];
  cc[1][0] = cptr[256 + col]; cc[1][1] = cptr[288 + col];
  __builtin_amdgcn_sched_barrier(0);

  if (wave == 3) {
    __builtin_amdgcn_global_load_lds(
        (const __attribute__((address_space(1))) void*)(ws + OFF_CB1 + b * 64 + lane),
        (__attribute__((address_space(3))) void*)(scb + 0), 4, 0, 0);
    __builtin_amdgcn_global_load_lds(
        (const __attribute__((address_space(1))) void*)(ws + OFF_CB2 + b * 64 + lane),
        (__attribute__((address_space(3))) void*)(scb + 64), 4, 0, 0);
    __builtin_amdgcn_global_load_lds(
        (const __attribute__((address_space(1))) void*)(ws + OFF_CB3 + b * 64 + lane),
        (__attribute__((address_space(3))) void*)(scb + 128), 4, 0, 0);
    // lanes 4..63 over-read harmlessly within ws; only scb[192..195] used
    __builtin_amdgcn_global_load_lds(
        (const __attribute__((address_space(1))) void*)(ws + OFF_CB4 + b * 4 + lane),
        (__attribute__((address_space(3))) void*)(scb + 192), 4, 0, 0);
  }
  __builtin_amdgcn_sched_barrier(0);

  const half8* __restrict__ gfr = (const half8*)ws;
  // g1: entries 0..767 = FE_L1 + FE_L2
  #pragma unroll
  for (int i = 0; i < 3; ++i) {
    const int e0 = wave * 64 + 256 * i;   // wave-uniform entry base
    __builtin_amdgcn_global_load_lds(
        (const __attribute__((address_space(1))) void*)(gfr + e0 + lane),
        (__attribute__((address_space(3))) void*)(sfr_raw + e0 * 8),
        16, 0, 0);
  }
  __builtin_amdgcn_sched_barrier(0);
  // g2: entries 768..1535 = FE_L3 + FE_L4
  #pragma unroll
  for (int i = 3; i < 6; ++i) {
    const int e0 = wave * 64 + 256 * i;
    __builtin_amdgcn_global_load_lds(
        (const __attribute__((address_space(1))) void*)(gfr + e0 + lane),
        (__attribute__((address_space(3))) void*)(sfr_raw + e0 * 8),
        16, 0, 0);
  }
  __builtin_amdgcn_sched_barrier(0);

  f32x16 acc[2][2];  // [mt][nt]
  half8 nbf[2][4];   // [nt][kt]

  // transition: pkrtz raw acc -> packed-f16 lrelu (pk_mul + pk_max)
  auto transition = [&]() {
    #pragma unroll
    for (int mt = 0; mt < 2; ++mt)
      #pragma unroll
      for (int nt = 0; nt < 2; ++nt) {
        #pragma unroll
        for (int h = 0; h < 2; ++h) {
          half2v pp[4];
          #pragma unroll
          for (int p = 0; p < 4; ++p) {
            fp16x2 t = __builtin_amdgcn_cvt_pkrtz(acc[mt][nt][8 * h + 2 * p],
                                                  acc[mt][nt][8 * h + 2 * p + 1]);
            pp[p] = __builtin_bit_cast(half2v, t);
          }
          half4v q0 = __builtin_shufflevector(pp[0], pp[1], 0, 1, 2, 3);
          half4v q1 = __builtin_shufflevector(pp[2], pp[3], 0, 1, 2, 3);
          half8 f = __builtin_shufflevector(q0, q1, 0, 1, 2, 3, 4, 5, 6, 7);
          half8 f2 = f * (_Float16)0.2f;           // v_pk_mul_f16
          nbf[nt][2 * mt + h] = __builtin_elementwise_max(f, f2);  // v_pk_max_f16
        }
      }
  };

  // acc init from LDS-staged cond biases (broadcast ds_read_b128 --
  // same-address broadcast is near-free on the LDS pipe; R15/R16 proved
  // replacing these with MFMA-fold or VMEM-select regresses)
  auto init_acc = [&](const float* __restrict__ cb) {
    #pragma unroll
    for (int mt = 0; mt < 2; ++mt)
      #pragma unroll
      for (int g = 0; g < 4; ++g) {
        const float4 f = *(const float4*)(cb + 32 * mt + 8 * g + q4);
        #pragma unroll
        for (int nt = 0; nt < 2; ++nt) {
          acc[mt][nt][4 * g + 0] = f.x;
          acc[mt][nt][4 * g + 1] = f.y;
          acc[mt][nt][4 * g + 2] = f.z;
          acc[mt][nt][4 * g + 3] = f.w;
        }
      }
  };

  #pragma unroll
  for (int t = 0; t < 2; ++t) {
    // ---- layer-1 B fragments: sinusoidal embedding, double-angle chain --
    half8 bf[2][2];  // [nt][kt]
    float mm[2];     // radius mask per nt
    {
      const float qm = hi ? 0.4f : 0.1f;  // 0.1 * 2^(2q)
      auto chain = [](float a, float* s, float* c) {
        float s0 = __sinf(a), c0 = __cosf(a);
        s[0] = s0; c[0] = c0;
        float s1 = 2.f * s0 * c0, c1 = (c0 - s0) * (c0 + s0);
        s[1] = s1; c[1] = c1;
        float s2 = 2.f * s1 * c1, c2 = (c1 - s1) * (c1 + s1);
        float s3 = 2.f * s2 * c2, c3 = (c2 - s2) * (c2 + s2);
        float s4 = 2.f * s3 * c3, c4 = (c3 - s3) * (c3 + s3);
        s[2] = s4; c[2] = c4;
        float s5 = 2.f * s4 * c4, c5 = (c4 - s4) * (c4 + s4);
        s[3] = s5; c[3] = c5;
      };
      #pragma unroll
      for (int nt = 0; nt < 2; ++nt) {
        const float2 ccv = cc[t][nt];
        const float rad = sqrtf(ccv.x * ccv.x + ccv.y * ccv.y);
        const float tt = fmaxf(rad - 1.0f, 0.0f);
        mm[nt] = 2.0f / (__expf(2.0f * tt) + 1.0f);
        float sx[4], cx[4], sy[4], cy[4];
        chain(ccv.x * qm, sx, cx);
        chain(ccv.y * qm, sy, cy);
        #pragma unroll
        for (int kt = 0; kt < 2; ++kt) {
          const int i0 = 2 * kt, i1 = 2 * kt + 1;
          half2v p0v = __builtin_bit_cast(half2v, __builtin_amdgcn_cvt_pkrtz(sx[i0], sy[i0]));
          half2v p1v = __builtin_bit_cast(half2v, __builtin_amdgcn_cvt_pkrtz(cx[i0], cy[i0]));
          half2v p2v = __builtin_bit_cast(half2v, __builtin_amdgcn_cvt_pkrtz(sx[i1], sy[i1]));
          half2v p3v = __builtin_bit_cast(half2v, __builtin_amdgcn_cvt_pkrtz(cx[i1], cy[i1]));
          half4v q0 = __builtin_shufflevector(p0v, p1v, 0, 1, 2, 3);
          half4v q1 = __builtin_shufflevector(p2v, p3v, 0, 1, 2, 3);
          bf[nt][kt] = __builtin_shufflevector(q0, q1, 0, 1, 2, 3, 4, 5, 6, 7);
        }
      }
    }

    if (t == 0) {
      // barrier #1: cc + cb + g1 (L1+L2 frags) complete; g2 in flight
      WAIT_VM3();
      __builtin_amdgcn_s_barrier();
      __builtin_amdgcn_sched_barrier(0);
    }

    // ---- layer 1: K=32 (Kt=2) ----
    init_acc(scb + 0);
    #pragma unroll
    for (int kt = 0; kt < 2; ++kt) {
      half8 a0 = sfr[FE_L1 + (0 * 2 + kt) * 64 + lane];
      half8 a1 = sfr[FE_L1 + (1 * 2 + kt) * 64 + lane];
      acc[0][0] = __builtin_amdgcn_mfma_f32_32x32x16_f16(a0, bf[0][kt], acc[0][0], 0, 0, 0);
      acc[0][1] = __builtin_amdgcn_mfma_f32_32x32x16_f16(a0, bf[1][kt], acc[0][1], 0, 0, 0);
      acc[1][0] = __builtin_amdgcn_mfma_f32_32x32x16_f16(a1, bf[0][kt], acc[1][0], 0, 0, 0);
      acc[1][1] = __builtin_amdgcn_mfma_f32_32x32x16_f16(a1, bf[1][kt], acc[1][1], 0, 0, 0);
    }
    transition();

    // ---- layer 2: K=64 (Kt=4) ----
    init_acc(scb + 64);
    #pragma unroll
    for (int kt = 0; kt < 4; ++kt) {
      half8 a0 = sfr[FE_L2 + (0 * 4 + kt) * 64 + lane];
      half8 a1 = sfr[FE_L2 + (1 * 4 + kt) * 64 + lane];
      acc[0][0] = __builtin_amdgcn_mfma_f32_32x32x16_f16(a0, nbf[0][kt], acc[0][0], 0, 0, 0);
      acc[0][1] = __builtin_amdgcn_mfma_f32_32x32x16_f16(a0, nbf[1][kt], acc[0][1], 0, 0, 0);
      acc[1][0] = __builtin_amdgcn_mfma_f32_32x32x16_f16(a1, nbf[0][kt], acc[1][0], 0, 0, 0);
      acc[1][1] = __builtin_amdgcn_mfma_f32_32x32x16_f16(a1, nbf[1][kt], acc[1][1], 0, 0, 0);
    }
    transition();

    if (t == 0) {
      // barrier #2: all staging (g2 = L3+L4 frags) complete
      WAIT_VM0();
      __builtin_amdgcn_s_barrier();
      __builtin_amdgcn_sched_barrier(0);
    }

    // ---- layer 3: K=64 (Kt=4) ----
    init_acc(scb + 128);
    #pragma unroll
    for (int kt = 0; kt < 4; ++kt) {
      half8 a0 = sfr[FE_L3 + (0 * 4 + kt) * 64 + lane];
      half8 a1 = sfr[FE_L3 + (1 * 4 + kt) * 64 + lane];
      acc[0][0] = __builtin_amdgcn_mfma_f32_32x32x16_f16(a0, nbf[0][kt], acc[0][0], 0, 0, 0);
      acc[0][1] = __builtin_amdgcn_mfma_f32_32x32x16_f16(a0, nbf[1][kt], acc[0][1], 0, 0, 0);
      acc[1][0] = __builtin_amdgcn_mfma_f32_32x32x16_f16(a1, nbf[0][kt], acc[1][0], 0, 0, 0);
      acc[1][1] = __builtin_amdgcn_mfma_f32_32x32x16_f16(a1, nbf[1][kt], acc[1][1], 0, 0, 0);
    }
    transition();

    // ---- layer 4: 64 -> 4 ----
    f32x16 acc4[2];
    {
      const float c0 = scb[192], c1 = scb[193], c2 = scb[194], c3 = scb[195];
      #pragma unroll
      for (int r = 0; r < 16; ++r) { acc4[0][r] = 0.f; acc4[1][r] = 0.f; }
      if (!hi) {
        acc4[0][0] = c0; acc4[0][1] = c1; acc4[0][2] = c2; acc4[0][3] = c3;
        acc4[1][0] = c0; acc4[1][1] = c1; acc4[1][2] = c2; acc4[1][3] = c3;
      }
    }
    #pragma unroll
    for (int kt = 0; kt < 4; ++kt) {
      half8 a0 = sfr[FE_L4 + kt * 64 + lane];
      acc4[0] = __builtin_amdgcn_mfma_f32_32x32x16_f16(a0, nbf[0][kt], acc4[0], 0, 0, 0);
      acc4[1] = __builtin_amdgcn_mfma_f32_32x32x16_f16(a0, nbf[1][kt], acc4[1], 0, 0, 0);
    }

    // epilogue: lanes 0..31 hold channels j=0..3 in regs 0..3
    if (!hi) {
      const int pbase = blockIdx.x * 512 + t * 256 + wave * 64 + col;
      #pragma unroll
      for (int nt = 0; nt < 2; ++nt) {
        const float m = mm[nt];
        out[pbase + 32 * nt] = make_float4(acc4[nt][0] * m, acc4[nt][1] * m,
                                           acc4[nt][2] * m, acc4[nt][3] * m);
      }
    }
  }
}

extern "C" void kernel_launch(void* const* d_in, const int* in_sizes, int n_in,
                              void* d_out, int out_size, void* d_ws, size_t ws_size,
                              hipStream_t stream) {
  const float* coords = (const float*)d_in[0];
  const float* c      = (const float*)d_in[1];
  const float* fu     = (const float*)d_in[2];
  const float* w1     = (const float*)d_in[3];
  const float* b1     = (const float*)d_in[4];
  const float* w2     = (const float*)d_in[5];
  const float* b2     = (const float*)d_in[6];
  const float* w3     = (const float*)d_in[7];
  const float* b3     = (const float*)d_in[8];
  const float* w4     = (const float*)d_in[9];
  const float* b4     = (const float*)d_in[10];
  float* ws  = (float*)d_ws;
  float* out = (float*)d_out;

  int npix = in_sizes[0] / 2;  // 8*256*256 = 524288

  // 12288 fragment threads + 6272 dot threads = 18560 -> 73 blocks
  prep_kernel<<<73, 256, 0, stream>>>(c, fu, w1, b1, w2, b2, w3, b3, w4, b4, ws);
  decoder_main<<<npix / 512, 256, 0, stream>>>(
      (const float2*)coords, ws, (float4*)out);
}